// Round 21
// baseline (119.505 us; speedup 1.0000x reference)
//
#include <hip/hip_runtime.h>
#include <hip/hip_bf16.h>

typedef __attribute__((ext_vector_type(8))) short short8v;   // bf16x8 fragment
typedef __attribute__((ext_vector_type(4))) float float4v;   // fp32x4 accum
typedef unsigned short ushort;
typedef unsigned int uint;

namespace {

constexpr int Hh = 192, Ww = 192, Cc = 16, Oo = 64, Bb = 4;
constexpr int TH = 4, TW = 32, NT = 128;     // 4x32 pixel tile, 128 threads (2 waves)
constexpr int HW = Hh * Ww;                  // 36864
constexpr int NPL = Bb * Cc;                 // 64 planes
constexpr int PVG_PLANE = 236 * 198;         // 46728 col-prefix plane
constexpr int PHG_PLANE = 198 * 236;         // 46728 row-prefix plane
constexpr size_t PLANE = (size_t)Bb * Oo * HW;                 // 9437184 floats
constexpr size_t PREFIX_FLOATS = (size_t)NPL * (PVG_PLANE + PHG_PLANE);  // 5981184
constexpr size_t WBF_FLOATS = 65536 / 2;                       // 65536 ushorts
constexpr size_t NEED_FULL = (PREFIX_FLOATS + WBF_FLOATS + 2 * PLANE) * 4;  // 99,553,280
constexpr int NPREF_T = 2 * NPL * 198;       // 25344 prefix threads
constexpr int NPREF_B = (NPREF_T + 63) / 64; // 396 blocks for prefix work
constexpr int NWPREP_B = 65536 / 64;         // 1024 blocks for wprep work

// Each feature = (vertical segment sum) + (horizontal segment sum), scaled by 1/n.
struct FD { int hasV; int vdj, vi0, vi1; int hasH; int hdi, hj0, hj1; float inv_n; };

constexpr FD FT[49] = {
    // 9 inner taps (i,j) row-major, n=1 (as V-singles)
    {1,-1,-1,-1, 0,0,0,0, 1.f}, {1, 0,-1,-1, 0,0,0,0, 1.f}, {1, 1,-1,-1, 0,0,0,0, 1.f},
    {1,-1, 0, 0, 0,0,0,0, 1.f}, {1, 0, 0, 0, 0,0,0,0, 1.f}, {1, 1, 0, 0, 0,0,0,0, 1.f},
    {1,-1, 1, 1, 0,0,0,0, 1.f}, {1, 0, 1, 1, 0,0,0,0, 1.f}, {1, 1, 1, 1, 0,0,0,0, 1.f},
    // ring5 (16)
    {1,-2,-2, 2, 1,-2,-1, 2, 1.f/9.f},
    {1,-1,-2, 2, 0,0,0,0, 0.2f},
    {1, 0,-2, 2, 0,0,0,0, 0.2f},
    {1, 1,-2, 2, 0,0,0,0, 0.2f},
    {1, 2,-2, 2, 1,-2,-2, 1, 1.f/9.f},
    {0,0,0,0, 1,-1,-2, 2, 0.2f},
    {0,0,0,0, 1,-1,-2, 2, 0.2f},
    {0,0,0,0, 1, 0,-2, 2, 0.2f},
    {0,0,0,0, 1, 0,-2, 2, 0.2f},
    {0,0,0,0, 1, 1,-2, 2, 0.2f},
    {0,0,0,0, 1, 1,-2, 2, 0.2f},
    {1,-2,-2, 2, 1, 2,-1, 2, 1.f/9.f},
    {1,-1,-2, 2, 0,0,0,0, 0.2f},
    {1, 0,-2, 2, 0,0,0,0, 0.2f},
    {1, 1,-2, 2, 0,0,0,0, 0.2f},
    {1, 2,-2, 2, 1, 2,-2, 1, 1.f/9.f},
    // ring7 (24)
    {1,-3,-3,11, 1,-3,-2,21, 1.f/39.f},
    {1,-2,-3,11, 0,0,0,0, 1.f/15.f},
    {1,-1,-3,11, 0,0,0,0, 1.f/15.f},
    {1, 0,-3,11, 0,0,0,0, 1.f/15.f},
    {1, 1,-3,11, 0,0,0,0, 1.f/15.f},
    {1, 2,-3,11, 0,0,0,0, 1.f/15.f},
    {1, 3,-3,11, 1,-3,-21, 2, 1.f/39.f},
    {0,0,0,0, 1,-2,-3,21, 0.04f},
    {0,0,0,0, 1,-2,-21,3, 0.04f},
    {0,0,0,0, 1,-1,-3,21, 0.04f},
    {0,0,0,0, 1,-1,-21,3, 0.04f},
    {0,0,0,0, 1, 0,-3,21, 0.04f},
    {0,0,0,0, 1, 0,-21,3, 0.04f},
    {0,0,0,0, 1, 1,-3,21, 0.04f},
    {0,0,0,0, 1, 1,-21,3, 0.04f},
    {0,0,0,0, 1, 2,-3,21, 0.04f},
    {0,0,0,0, 1, 2,-21,3, 0.04f},
    {1,-3,-11,3, 1, 3,-2,21, 1.f/39.f},
    {1,-2,-11,3, 0,0,0,0, 1.f/15.f},
    {1,-1,-11,3, 0,0,0,0, 1.f/15.f},
    {1, 0,-11,3, 0,0,0,0, 1.f/15.f},
    {1, 1,-11,3, 0,0,0,0, 1.f/15.f},
    {1, 2,-11,3, 0,0,0,0, 1.f/15.f},
    {1, 3,-11,3, 1, 3,-21,2, 1.f/39.f},
};

// reflect-pad(3) + clip index map; valid for u in [-21, 213]
__device__ __forceinline__ int mapIdx(int u) {
    if (u < 0) { u = -u; if (u > 3) u = 3; }
    else if (u > 191) { u = 382 - u; if (u < 188) u = 188; }
    return u;
}

// RNE fp32->bf16 bits (native; pairs fuse to v_cvt_pk_bf16_f32)
__device__ __forceinline__ ushort f2bf(float f) {
    __hip_bfloat16 h = __float2bfloat16(f);
    return __builtin_bit_cast(ushort, h);
}

// Merged prep: blocks [0,396) build prefix planes; blocks [396,1420) convert weights.
__global__ __launch_bounds__(64)
void prep(const float* __restrict__ x, const float* __restrict__ wgt,
          float* __restrict__ pvg, float* __restrict__ phg, ushort* __restrict__ wbf)
{
    if (blockIdx.x >= NPREF_B) {
        const int t = (blockIdx.x - NPREF_B) * 64 + threadIdx.x;   // 65536 entries
        const int k = t & 63, o = (t >> 6) & 63, c = t >> 12;
        wbf[t] = (k < 49) ? f2bf(wgt[o * 784 + c * 49 + k]) : (ushort)0;
        return;
    }
    const int t = blockIdx.x * 64 + threadIdx.x;       // 0..25343
    if (t >= NPREF_T) return;
    const bool isPV = t < NPL * 198;
    const int u = isPV ? t : t - NPL * 198;
    const int plane = u / 198;
    const int q     = u - plane * 198;
    const float* xp = x + (size_t)plane * HW;
    if (isPV) {
        const int wsrc = mapIdx(q - 3);                // fixed source col
        float* pv = pvg + (size_t)plane * PVG_PLANE + q;
        float r = 0.f;
        pv[0] = 0.f;
        for (int t0 = 0; t0 < 235; t0 += 5) {          // 47 groups; 5 loads batched
            float v0 = xp[mapIdx(t0 - 21) * Ww + wsrc];
            float v1 = xp[mapIdx(t0 - 20) * Ww + wsrc];
            float v2 = xp[mapIdx(t0 - 19) * Ww + wsrc];
            float v3 = xp[mapIdx(t0 - 18) * Ww + wsrc];
            float v4 = xp[mapIdx(t0 - 17) * Ww + wsrc];
            float* pd = pv + (size_t)(t0 + 1) * 198;
            r += v0; pd[0]   = r;
            r += v1; pd[198] = r;
            r += v2; pd[396] = r;
            r += v3; pd[594] = r;
            r += v4; pd[792] = r;
        }
    } else {
        const int rsrc = mapIdx(q - 3) * Ww;           // fixed source row
        float* ph = phg + (size_t)plane * PHG_PLANE + (size_t)q * 236;
        float r = 0.f;
        ph[0] = 0.f;
        for (int t0 = 0; t0 < 235; t0 += 5) {
            float v0 = xp[rsrc + mapIdx(t0 - 21)];
            float v1 = xp[rsrc + mapIdx(t0 - 20)];
            float v2 = xp[rsrc + mapIdx(t0 - 19)];
            float v3 = xp[rsrc + mapIdx(t0 - 18)];
            float v4 = xp[rsrc + mapIdx(t0 - 17)];
            float* pd = ph + t0 + 1;
            r += v0; pd[0] = r;
            r += v1; pd[1] = r;
            r += v2; pd[2] = r;
            r += v3; pd[3] = r;
            r += v4; pd[4] = r;
        }
    }
}

// NC = channels per block; DIRECT: write out+bias, else fp32 partial to dst.
template<int NC, bool DIRECT>
__global__ __launch_bounds__(NT, 3)
void fova21(const ushort* __restrict__ wbf, const float* __restrict__ bias,
            const float* __restrict__ pvg, const float* __restrict__ phg,
            float* __restrict__ dst)
{
    constexpr int HALVES = Cc / NC;
    __shared__ ushort featB[NT][66];   // bf16 feat [pixel][k], padded stride
    __shared__ ushort wlds[64][72];    // bf16 weight slice [o][k], 144B rows

    const int tid  = threadIdx.x;
    const int lane = tid & 63;
    const int wv   = tid >> 6;          // wave id 0/1
    const int w0   = blockIdx.x * TW;
    const int h0   = blockIdx.y * TH;
    const int bz   = blockIdx.z;
    const int b    = (HALVES == 1) ? bz : (bz >> 1);
    const int half = (HALVES == 1) ? 0  : (bz & 1);
    const int c0   = half * NC;
    const int ph_  = tid >> 5;          // pixel row 0..3 (tid == pixel id)
    const int pw   = tid & 31;
    const int h    = h0 + ph_, w = w0 + pw;

    float4v acc[4][4];
#pragma unroll
    for (int i = 0; i < 4; ++i)
#pragma unroll
        for (int j = 0; j < 4; ++j) acc[i][j] = (float4v)(0.f);

    // one-time pad zeroing (ordered before first MFMA by the in-loop barrier)
#pragma unroll
    for (int f = 49; f < 64; ++f) featB[tid][f] = 0;

    // per-thread prefix bases (plane stride advanced per c)
    const float* pvb = pvg + (size_t)(b * Cc + c0) * PVG_PLANE + (size_t)(h + 22) * 198 + (w + 3);
    const float* phb = phg + (size_t)(b * Cc + c0) * PHG_PLANE + (size_t)(h + 3) * 236 + (w + 21);
    const ushort* wsrc0 = wbf + (c0 << 12) + tid * 32;   // tid*4 chunks of 8 ushorts

    for (int cc = 0; cc < NC; ++cc) {
        // ---- W(c) staging loads: ISSUE EARLY (4x b128, 64B contiguous per thread) ----
        short8v wreg[4];
#pragma unroll
        for (int q = 0; q < 4; ++q)
            wreg[q] = *(const short8v*)(&wsrc0[q * 8]);

        // ---- features: 6 groups of 8 — cluster loads, then combine+pack (MLP) ----
        {
            const float* pv = pvb;
            const float* phv = phb;
            uint* fb32 = reinterpret_cast<uint*>(&featB[tid][0]);
#pragma unroll
            for (int g = 0; g < 6; ++g) {
                float pvA[8], pvB[8], phA[8], phB[8];
#pragma unroll
                for (int i = 0; i < 8; ++i) {          // LOAD CLUSTER (all independent)
                    const int f = g * 8 + i;
                    if (FT[f].hasV) {
                        pvA[i] = pv[FT[f].vi1 * 198 + FT[f].vdj];
                        pvB[i] = pv[(FT[f].vi0 - 1) * 198 + FT[f].vdj];
                    }
                    if (FT[f].hasH) {
                        phA[i] = phv[FT[f].hdi * 236 + (FT[f].hj1 + 1)];
                        phB[i] = phv[FT[f].hdi * 236 + FT[f].hj0];
                    }
                }
                float sv[8];
#pragma unroll
                for (int i = 0; i < 8; ++i) {          // COMBINE
                    const int f = g * 8 + i;
                    float s = 0.f;
                    if (FT[f].hasV) s += pvA[i] - pvB[i];
                    if (FT[f].hasH) s += phA[i] - phB[i];
                    sv[i] = s * FT[f].inv_n;
                }
#pragma unroll
                for (int j = 0; j < 4; ++j)            // PACK (cvt_pk fused)
                    fb32[g * 4 + j] = (uint)f2bf(sv[2 * j]) | ((uint)f2bf(sv[2 * j + 1]) << 16);
            }
            // f = 48 (last feature)
            {
                float s = pv[FT[48].vi1 * 198 + FT[48].vdj] - pv[(FT[48].vi0 - 1) * 198 + FT[48].vdj]
                        + phv[FT[48].hdi * 236 + (FT[48].hj1 + 1)] - phv[FT[48].hdi * 236 + FT[48].hj0];
                featB[tid][48] = f2bf(s * FT[48].inv_n);
            }
        }

        // ---- write wlds (W regs arrived long ago); single barrier ----
        {
            const int base = tid * 4;          // chunk index
#pragma unroll
            for (int q = 0; q < 4; ++q) {
                const int idx = base + q;
                const int o = idx >> 3, grp = idx & 7;
                *(short8v*)(&wlds[o][grp * 8]) = wreg[q];
            }
        }
        __syncthreads();

        // ---- MFMA(c): A from wlds (ds_read_b128), B from featB ----
        {
            const int olo = lane & 15, kg = lane >> 4;
#pragma unroll
            for (int kc = 0; kc < 2; ++kc) {
                const int k0 = kc * 32 + kg * 8;          // 16B aligned in wlds
                short8v afr[4];
#pragma unroll
                for (int ob = 0; ob < 4; ++ob) {
                    const int o = ob * 16 + olo;
                    afr[ob] = *(const short8v*)(&wlds[o][k0]);
                }
                short8v bfr[4];
#pragma unroll
                for (int nb = 0; nb < 4; ++nb) {
                    const int p = wv * 64 + nb * 16 + olo;
                    const uint* bp = (const uint*)(&featB[p][k0]);
                    uint4 u;
                    u.x = bp[0]; u.y = bp[1]; u.z = bp[2]; u.w = bp[3];
                    bfr[nb] = __builtin_bit_cast(short8v, u);
                }
#pragma unroll
                for (int ob = 0; ob < 4; ++ob)
#pragma unroll
                    for (int nb = 0; nb < 4; ++nb)
                        acc[ob][nb] = __builtin_amdgcn_mfma_f32_16x16x32_bf16(
                            afr[ob], bfr[nb], acc[ob][nb], 0, 0, 0);
            }
        }
        __syncthreads();   // wlds/featB rewritten next c

        pvb += PVG_PLANE; phb += PHG_PLANE; wsrc0 += 4096;
    }

    // ---- epilogue: D frag: col(pixel)=lane&15, row(o)=(lane>>4)*4+reg ----
    float* dbase = DIRECT ? dst : (dst + (size_t)half * PLANE);
#pragma unroll
    for (int ob = 0; ob < 4; ++ob)
#pragma unroll
        for (int nb = 0; nb < 4; ++nb) {
            const int p = wv * 64 + nb * 16 + (lane & 15);
            const int hh = h0 + (p >> 5), ww2 = w0 + (p & 31);
            const int o0 = ob * 16 + ((lane >> 4) << 2);
            float4v a = acc[ob][nb];
#pragma unroll
            for (int r = 0; r < 4; ++r) {
                const int o = o0 + r;
                float v = DIRECT ? (a[r] + bias[o]) : a[r];
                dbase[(((size_t)b * Oo + o) * Hh + hh) * Ww + ww2] = v;
            }
        }
}

// out = p0 + p1 + bias (memory-bound, float4, grid-stride)
__global__ __launch_bounds__(256)
void reduce2(const float4* __restrict__ p, const float* __restrict__ bias,
             float4* __restrict__ out)
{
    const int n4 = (int)(PLANE / 4);            // 2359296
    for (int i = blockIdx.x * 256 + threadIdx.x; i < n4; i += gridDim.x * 256) {
        float4 a = p[i];
        float4 b = p[i + n4];
        const int o = (i / 9216) & 63;          // 9216 float4s per (b,o) plane
        const float bo = bias[o];
        float4 r;
        r.x = a.x + b.x + bo; r.y = a.y + b.y + bo;
        r.z = a.z + b.z + bo; r.w = a.w + b.w + bo;
        out[i] = r;
    }
}

} // namespace

extern "C" void kernel_launch(void* const* d_in, const int* in_sizes, int n_in,
                              void* d_out, int out_size, void* d_ws, size_t ws_size,
                              hipStream_t stream) {
    (void)in_sizes; (void)n_in; (void)out_size;
    const float* x    = (const float*)d_in[0];
    const float* wgt  = (const float*)d_in[1];
    const float* bias = (const float*)d_in[2];
    float* out        = (float*)d_out;

    float* pvg  = (float*)d_ws;
    float* phg  = pvg + (size_t)NPL * PVG_PLANE;
    ushort* wbf = (ushort*)(phg + (size_t)NPL * PHG_PLANE);

    prep<<<dim3(NPREF_B + NWPREP_B), dim3(64), 0, stream>>>(x, wgt, pvg, phg, wbf);

    dim3 block(NT);
    if (ws_size >= NEED_FULL) {
        float* part = (float*)d_ws + PREFIX_FLOATS + WBF_FLOATS;
        dim3 grid(Ww / TW, Hh / TH, Bb * 2);          // 2304 blocks, 8 channels each
        fova21<8, false><<<grid, block, 0, stream>>>(wbf, bias, pvg, phg, part);
        reduce2<<<dim3(2048), dim3(256), 0, stream>>>((const float4*)part, bias, (float4*)out);
    } else {
        dim3 grid(Ww / TW, Hh / TH, Bb);              // 1152 blocks, 16 channels
        fova21<16, true><<<grid, block, 0, stream>>>(wbf, bias, pvg, phg, out);
    }
}

// Round 22
// 113.024 us; speedup vs baseline: 1.0573x; 1.0573x over previous
//
#include <hip/hip_runtime.h>
#include <hip/hip_bf16.h>

typedef __attribute__((ext_vector_type(8))) short short8v;   // bf16x8 fragment
typedef __attribute__((ext_vector_type(4))) float float4v;   // fp32x4 accum
typedef unsigned short ushort;
typedef unsigned int uint;

namespace {

constexpr int Hh = 192, Ww = 192, Cc = 16, Oo = 64, Bb = 4;
constexpr int TH = 4, TW = 32, NT = 128;     // 4x32 pixel tile, 128 threads (2 waves)
constexpr int HW = Hh * Ww;                  // 36864
constexpr int NPL = Bb * Cc;                 // 64 planes
constexpr int PVG_PLANE = 236 * 198;         // col-prefix plane
constexpr int PHG_PLANE = 198 * 236;         // row-prefix plane
constexpr size_t PLANE = (size_t)Bb * Oo * HW;                 // 9437184 floats
constexpr size_t PREFIX_FLOATS = (size_t)NPL * (PVG_PLANE + PHG_PLANE);
constexpr size_t WBF_FLOATS = 65536 / 2;
constexpr size_t NEED_FULL = (PREFIX_FLOATS + WBF_FLOATS + 2 * PLANE) * 4;  // 99,553,280
constexpr int NPREF_T = 2 * NPL * 198;       // 25344 prefix threads
constexpr int NPREF_B = (NPREF_T + 63) / 64; // 396
constexpr int NWPREP_B = 65536 / 64;         // 1024

// Each feature = (vertical segment sum) + (horizontal segment sum), scaled by 1/n.
struct FD { int hasV; int vdj, vi0, vi1; int hasH; int hdi, hj0, hj1; float inv_n; };

constexpr FD FT[49] = {
    // 9 inner taps (i,j) row-major, n=1 (as V-singles)
    {1,-1,-1,-1, 0,0,0,0, 1.f}, {1, 0,-1,-1, 0,0,0,0, 1.f}, {1, 1,-1,-1, 0,0,0,0, 1.f},
    {1,-1, 0, 0, 0,0,0,0, 1.f}, {1, 0, 0, 0, 0,0,0,0, 1.f}, {1, 1, 0, 0, 0,0,0,0, 1.f},
    {1,-1, 1, 1, 0,0,0,0, 1.f}, {1, 0, 1, 1, 0,0,0,0, 1.f}, {1, 1, 1, 1, 0,0,0,0, 1.f},
    // ring5 (16)
    {1,-2,-2, 2, 1,-2,-1, 2, 1.f/9.f},
    {1,-1,-2, 2, 0,0,0,0, 0.2f},
    {1, 0,-2, 2, 0,0,0,0, 0.2f},
    {1, 1,-2, 2, 0,0,0,0, 0.2f},
    {1, 2,-2, 2, 1,-2,-2, 1, 1.f/9.f},
    {0,0,0,0, 1,-1,-2, 2, 0.2f},
    {0,0,0,0, 1,-1,-2, 2, 0.2f},
    {0,0,0,0, 1, 0,-2, 2, 0.2f},
    {0,0,0,0, 1, 0,-2, 2, 0.2f},
    {0,0,0,0, 1, 1,-2, 2, 0.2f},
    {0,0,0,0, 1, 1,-2, 2, 0.2f},
    {1,-2,-2, 2, 1, 2,-1, 2, 1.f/9.f},
    {1,-1,-2, 2, 0,0,0,0, 0.2f},
    {1, 0,-2, 2, 0,0,0,0, 0.2f},
    {1, 1,-2, 2, 0,0,0,0, 0.2f},
    {1, 2,-2, 2, 1, 2,-2, 1, 1.f/9.f},
    // ring7 (24)
    {1,-3,-3,11, 1,-3,-2,21, 1.f/39.f},
    {1,-2,-3,11, 0,0,0,0, 1.f/15.f},
    {1,-1,-3,11, 0,0,0,0, 1.f/15.f},
    {1, 0,-3,11, 0,0,0,0, 1.f/15.f},
    {1, 1,-3,11, 0,0,0,0, 1.f/15.f},
    {1, 2,-3,11, 0,0,0,0, 1.f/15.f},
    {1, 3,-3,11, 1,-3,-21, 2, 1.f/39.f},
    {0,0,0,0, 1,-2,-3,21, 0.04f},
    {0,0,0,0, 1,-2,-21,3, 0.04f},
    {0,0,0,0, 1,-1,-3,21, 0.04f},
    {0,0,0,0, 1,-1,-21,3, 0.04f},
    {0,0,0,0, 1, 0,-3,21, 0.04f},
    {0,0,0,0, 1, 0,-21,3, 0.04f},
    {0,0,0,0, 1, 1,-3,21, 0.04f},
    {0,0,0,0, 1, 1,-21,3, 0.04f},
    {0,0,0,0, 1, 2,-3,21, 0.04f},
    {0,0,0,0, 1, 2,-21,3, 0.04f},
    {1,-3,-11,3, 1, 3,-2,21, 1.f/39.f},
    {1,-2,-11,3, 0,0,0,0, 1.f/15.f},
    {1,-1,-11,3, 0,0,0,0, 1.f/15.f},
    {1, 0,-11,3, 0,0,0,0, 1.f/15.f},
    {1, 1,-11,3, 0,0,0,0, 1.f/15.f},
    {1, 2,-11,3, 0,0,0,0, 1.f/15.f},
    {1, 3,-11,3, 1, 3,-21,2, 1.f/39.f},
};

// reflect-pad(3) + clip index map; valid for u in [-21, 213]
__device__ __forceinline__ int mapIdx(int u) {
    if (u < 0) { u = -u; if (u > 3) u = 3; }
    else if (u > 191) { u = 382 - u; if (u < 188) u = 188; }
    return u;
}

// RNE fp32->bf16 bits (native; pairs fuse to v_cvt_pk_bf16_f32)
__device__ __forceinline__ ushort f2bf(float f) {
    __hip_bfloat16 h = __float2bfloat16(f);
    return __builtin_bit_cast(ushort, h);
}

// Merged prep: blocks [0,396) build prefix planes; rest convert weights.
__global__ __launch_bounds__(64)
void prep(const float* __restrict__ x, const float* __restrict__ wgt,
          float* __restrict__ pvg, float* __restrict__ phg, ushort* __restrict__ wbf)
{
    if (blockIdx.x >= NPREF_B) {
        const int t = (blockIdx.x - NPREF_B) * 64 + threadIdx.x;   // 65536 entries
        const int k = t & 63, o = (t >> 6) & 63, c = t >> 12;
        wbf[t] = (k < 49) ? f2bf(wgt[o * 784 + c * 49 + k]) : (ushort)0;
        return;
    }
    const int t = blockIdx.x * 64 + threadIdx.x;       // 0..25343
    if (t >= NPREF_T) return;
    const bool isPV = t < NPL * 198;
    const int u = isPV ? t : t - NPL * 198;
    const int plane = u / 198;
    const int q     = u - plane * 198;
    const float* xp = x + (size_t)plane * HW;
    if (isPV) {
        const int wsrc = mapIdx(q - 3);
        float* pv = pvg + (size_t)plane * PVG_PLANE + q;
        float r = 0.f;
        pv[0] = 0.f;
        for (int t0 = 0; t0 < 235; t0 += 5) {
            float v0 = xp[mapIdx(t0 - 21) * Ww + wsrc];
            float v1 = xp[mapIdx(t0 - 20) * Ww + wsrc];
            float v2 = xp[mapIdx(t0 - 19) * Ww + wsrc];
            float v3 = xp[mapIdx(t0 - 18) * Ww + wsrc];
            float v4 = xp[mapIdx(t0 - 17) * Ww + wsrc];
            float* pd = pv + (size_t)(t0 + 1) * 198;
            r += v0; pd[0]   = r;
            r += v1; pd[198] = r;
            r += v2; pd[396] = r;
            r += v3; pd[594] = r;
            r += v4; pd[792] = r;
        }
    } else {
        const int rsrc = mapIdx(q - 3) * Ww;
        float* ph = phg + (size_t)plane * PHG_PLANE + (size_t)q * 236;
        float r = 0.f;
        ph[0] = 0.f;
        for (int t0 = 0; t0 < 235; t0 += 5) {
            float v0 = xp[rsrc + mapIdx(t0 - 21)];
            float v1 = xp[rsrc + mapIdx(t0 - 20)];
            float v2 = xp[rsrc + mapIdx(t0 - 19)];
            float v3 = xp[rsrc + mapIdx(t0 - 18)];
            float v4 = xp[rsrc + mapIdx(t0 - 17)];
            float* pd = ph + t0 + 1;
            r += v0; pd[0] = r;
            r += v1; pd[1] = r;
            r += v2; pd[2] = r;
            r += v3; pd[3] = r;
            r += v4; pd[4] = r;
        }
    }
}

// NC = channels per block; DIRECT: write out+bias, else fp32 partial to dst.
template<int NC, bool DIRECT>
__global__ __launch_bounds__(NT, 3)
void fova22(const ushort* __restrict__ wbf, const float* __restrict__ bias,
            const float* __restrict__ pvg, const float* __restrict__ phg,
            float* __restrict__ dst)
{
    constexpr int HALVES = Cc / NC;
    __shared__ ushort featB[NT][66];   // 16896 B
    __shared__ ushort wlds[64][72];    //  9216 B
    __shared__ float  pvt[27][40];     //  4320 B: pvg rows h0+10..h0+36, cols w0..w0+37
    __shared__ float  pht[10][76];     //  3040 B: phg rows h0..h0+9,   cols w0..w0+74

    const int tid  = threadIdx.x;
    const int lane = tid & 63;
    const int wv   = tid >> 6;          // wave id 0/1
    const int w0   = blockIdx.x * TW;
    const int h0   = blockIdx.y * TH;
    const int bz   = blockIdx.z;
    const int b    = (HALVES == 1) ? bz : (bz >> 1);
    const int half = (HALVES == 1) ? 0  : (bz & 1);
    const int c0   = half * NC;
    const int ph_  = tid >> 5;          // pixel row 0..3 (tid == pixel id)
    const int pw   = tid & 31;

    float4v acc[4][4];
#pragma unroll
    for (int i = 0; i < 4; ++i)
#pragma unroll
        for (int j = 0; j < 4; ++j) acc[i][j] = (float4v)(0.f);

#pragma unroll
    for (int f = 49; f < 64; ++f) featB[tid][f] = 0;

    // tile sources (advance by plane stride per c)
    const float* pvsrc = pvg + (size_t)(b * Cc + c0) * PVG_PLANE + (size_t)(h0 + 10) * 198 + w0;
    const float* phsrc = phg + (size_t)(b * Cc + c0) * PHG_PLANE + (size_t)h0 * 236 + w0;
    const ushort* wsrc0 = wbf + (c0 << 12) + tid * 32;

    // ---- prologue: stage tiles(c0) ----
    for (int idx = tid; idx < 27 * 38; idx += NT) {
        int r = idx / 38, c = idx - r * 38;
        pvt[r][c] = pvsrc[r * 198 + c];
    }
    for (int idx = tid; idx < 10 * 75; idx += NT) {
        int r = idx / 75, c = idx - r * 75;
        pht[r][c] = phsrc[r * 236 + c];
    }
    __syncthreads();

    for (int cc = 0; cc < NC; ++cc) {
        // ---- W(c) regs: issue early ----
        short8v wreg[4];
#pragma unroll
        for (int q = 0; q < 4; ++q)
            wreg[q] = *(const short8v*)(&wsrc0[q * 8]);

        // ---- features from LDS tiles (identical arithmetic/order to fova20) ----
        {
            auto FV = [&](int f) -> float {
                float s = 0.f;
                if (FT[f].hasV)
                    s += pvt[ph_ + FT[f].vi1 + 12][pw + 3 + FT[f].vdj]
                       - pvt[ph_ + FT[f].vi0 + 11][pw + 3 + FT[f].vdj];
                if (FT[f].hasH)
                    s += pht[ph_ + 3 + FT[f].hdi][pw + 21 + FT[f].hj1 + 1]
                       - pht[ph_ + 3 + FT[f].hdi][pw + 21 + FT[f].hj0];
                return s * FT[f].inv_n;
            };
            uint* fb32 = reinterpret_cast<uint*>(&featB[tid][0]);
#pragma unroll
            for (int j = 0; j < 24; ++j)
                fb32[j] = (uint)f2bf(FV(2 * j)) | ((uint)f2bf(FV(2 * j + 1)) << 16);
            featB[tid][48] = f2bf(FV(48));
        }
        // ---- wlds write (W regs long since arrived) ----
        {
            const int base = tid * 4;
#pragma unroll
            for (int q = 0; q < 4; ++q) {
                const int idx = base + q;
                *(short8v*)(&wlds[idx >> 3][(idx & 7) * 8]) = wreg[q];
            }
        }
        __syncthreads();   // featB/wlds ready; all tile reads done

        // ---- stage-loads(c+1): issue BEFORE MFMA (latency hides under it) ----
        float pvr[9], phr[6];
        const bool more = (cc + 1 < NC);
        if (more) {
            const float* pvn = pvsrc + PVG_PLANE;
            const float* phn = phsrc + PHG_PLANE;
#pragma unroll
            for (int k = 0; k < 9; ++k) {
                int idx = tid + k * NT;
                if (idx < 27 * 38) pvr[k] = pvn[(idx / 38) * 198 + (idx % 38)];
            }
#pragma unroll
            for (int k = 0; k < 6; ++k) {
                int idx = tid + k * NT;
                if (idx < 10 * 75) phr[k] = phn[(idx / 75) * 236 + (idx % 75)];
            }
        }

        // ---- MFMA(c): A from wlds (b128), B from featB ----
        {
            const int olo = lane & 15, kg = lane >> 4;
#pragma unroll
            for (int kc = 0; kc < 2; ++kc) {
                const int k0 = kc * 32 + kg * 8;
                short8v afr[4];
#pragma unroll
                for (int ob = 0; ob < 4; ++ob) {
                    const int o = ob * 16 + olo;
                    afr[ob] = *(const short8v*)(&wlds[o][k0]);
                }
                short8v bfr[4];
#pragma unroll
                for (int nb = 0; nb < 4; ++nb) {
                    const int p = wv * 64 + nb * 16 + olo;
                    const uint* bp = (const uint*)(&featB[p][k0]);
                    uint4 u;
                    u.x = bp[0]; u.y = bp[1]; u.z = bp[2]; u.w = bp[3];
                    bfr[nb] = __builtin_bit_cast(short8v, u);
                }
#pragma unroll
                for (int ob = 0; ob < 4; ++ob)
#pragma unroll
                    for (int nb = 0; nb < 4; ++nb)
                        acc[ob][nb] = __builtin_amdgcn_mfma_f32_16x16x32_bf16(
                            afr[ob], bfr[nb], acc[ob][nb], 0, 0, 0);
            }
        }

        // ---- write tiles(c+1) (disjoint from featB/wlds; reads done pre-barrier) ----
        if (more) {
#pragma unroll
            for (int k = 0; k < 9; ++k) {
                int idx = tid + k * NT;
                if (idx < 27 * 38) pvt[idx / 38][idx % 38] = pvr[k];
            }
#pragma unroll
            for (int k = 0; k < 6; ++k) {
                int idx = tid + k * NT;
                if (idx < 10 * 75) pht[idx / 75][idx % 75] = phr[k];
            }
        }
        __syncthreads();   // MFMA done; tiles(c+1) ready

        pvsrc += PVG_PLANE; phsrc += PHG_PLANE; wsrc0 += 4096;
    }

    // ---- epilogue ----
    float* dbase = DIRECT ? dst : (dst + (size_t)half * PLANE);
#pragma unroll
    for (int ob = 0; ob < 4; ++ob)
#pragma unroll
        for (int nb = 0; nb < 4; ++nb) {
            const int p = wv * 64 + nb * 16 + (lane & 15);
            const int hh = h0 + (p >> 5), ww2 = w0 + (p & 31);
            const int o0 = ob * 16 + ((lane >> 4) << 2);
            float4v a = acc[ob][nb];
#pragma unroll
            for (int r = 0; r < 4; ++r) {
                const int o = o0 + r;
                float v = DIRECT ? (a[r] + bias[o]) : a[r];
                dbase[(((size_t)b * Oo + o) * Hh + hh) * Ww + ww2] = v;
            }
        }
}

// out = p0 + p1 + bias (memory-bound, float4, grid-stride)
__global__ __launch_bounds__(256)
void reduce2(const float4* __restrict__ p, const float* __restrict__ bias,
             float4* __restrict__ out)
{
    const int n4 = (int)(PLANE / 4);
    for (int i = blockIdx.x * 256 + threadIdx.x; i < n4; i += gridDim.x * 256) {
        float4 a = p[i];
        float4 b = p[i + n4];
        const int o = (i / 9216) & 63;
        const float bo = bias[o];
        float4 r;
        r.x = a.x + b.x + bo; r.y = a.y + b.y + bo;
        r.z = a.z + b.z + bo; r.w = a.w + b.w + bo;
        out[i] = r;
    }
}

} // namespace

extern "C" void kernel_launch(void* const* d_in, const int* in_sizes, int n_in,
                              void* d_out, int out_size, void* d_ws, size_t ws_size,
                              hipStream_t stream) {
    (void)in_sizes; (void)n_in; (void)out_size;
    const float* x    = (const float*)d_in[0];
    const float* wgt  = (const float*)d_in[1];
    const float* bias = (const float*)d_in[2];
    float* out        = (float*)d_out;

    float* pvg  = (float*)d_ws;
    float* phg  = pvg + (size_t)NPL * PVG_PLANE;
    ushort* wbf = (ushort*)(phg + (size_t)NPL * PHG_PLANE);

    prep<<<dim3(NPREF_B + NWPREP_B), dim3(64), 0, stream>>>(x, wgt, pvg, phg, wbf);

    dim3 block(NT);
    if (ws_size >= NEED_FULL) {
        float* part = (float*)d_ws + PREFIX_FLOATS + WBF_FLOATS;
        dim3 grid(Ww / TW, Hh / TH, Bb * 2);          // 2304 blocks, 8 channels each
        fova22<8, false><<<grid, block, 0, stream>>>(wbf, bias, pvg, phg, part);
        reduce2<<<dim3(2048), dim3(256), 0, stream>>>((const float4*)part, bias, (float4*)out);
    } else {
        dim3 grid(Ww / TW, Hh / TH, Bb);              // 1152 blocks, 16 channels
        fova22<16, true><<<grid, block, 0, stream>>>(wbf, bias, pvg, phg, out);
    }
}